// Round 6
// baseline (282.876 us; speedup 1.0000x reference)
//
#include <hip/hip_runtime.h>
#include <hip/hip_bf16.h>
#include <cstdint>
#include <cstddef>

#define N_TOK 8192
#define D_IN  1024
#define D_OUT 1024
#define N_EXP 8
#define KTOT  (N_EXP * D_IN)

typedef __attribute__((ext_vector_type(8))) short short8;
typedef __attribute__((ext_vector_type(8))) unsigned short ushort8;
typedef __attribute__((ext_vector_type(4))) float f32x4;

__device__ __forceinline__ unsigned short f2bf(float f) {
    union { float f; unsigned int u; } v; v.f = f;
    return (unsigned short)((v.u + 0x7FFFu + ((v.u >> 16) & 1u)) >> 16);
}

__device__ __forceinline__ void load_lds16(const void* g, void* l) {
    __builtin_amdgcn_global_load_lds(
        (const __attribute__((address_space(1))) void*)g,
        (__attribute__((address_space(3))) void*)l,
        16, 0, 0);
}

// ---------------------------------------------------------------------------
// Fused prep, 4096 blocks (unchanged from R5):
//   [0,2048)    : W[e][i][o] fp32 -> Wt[o][e*1024+i] bf16 (64x64 transpose)
//   [2048,4096) : gate softmax + x->bf16, one wave per token (4 tok/block)
// ---------------------------------------------------------------------------
__global__ __launch_bounds__(256) void prep_kernel(
    const float* __restrict__ x, const float* __restrict__ gW,
    const float* __restrict__ gbias, const float* __restrict__ W,
    unsigned short* __restrict__ xb, unsigned short* __restrict__ Wt,
    float* __restrict__ g_t) {
    const int b = blockIdx.x;
    const int t = threadIdx.x;

    if (b < 2048) {
        __shared__ float tile[64][65];
        const int e  = b >> 8;
        const int i0 = ((b >> 4) & 15) * 64;
        const int o0 = (b & 15) * 64;

        const int rr = t >> 4;
        const int rc = (t & 15) * 4;
#pragma unroll
        for (int j = 0; j < 4; ++j) {
            const float4 v = *(const float4*)(
                W + ((size_t)e * D_IN + (i0 + rr + 16 * j)) * D_OUT + o0 + rc);
            tile[rr + 16 * j][rc + 0] = v.x;
            tile[rr + 16 * j][rc + 1] = v.y;
            tile[rr + 16 * j][rc + 2] = v.z;
            tile[rr + 16 * j][rc + 3] = v.w;
        }
        __syncthreads();
        const int ow = t >> 2;
        const int c  = (t & 3) * 16;
        ushort8 v0, v1;
#pragma unroll
        for (int j = 0; j < 8; ++j) v0[j] = f2bf(tile[c + j][ow]);
#pragma unroll
        for (int j = 0; j < 8; ++j) v1[j] = f2bf(tile[c + 8 + j][ow]);
        unsigned short* dst = Wt + (size_t)(o0 + ow) * KTOT + e * D_IN + i0 + c;
        *(ushort8*)dst = v0;
        *(ushort8*)(dst + 8) = v1;
    } else {
        const int lane = t & 63;
        const int n    = (b - 2048) * 4 + (t >> 6);

        float acc[8];
#pragma unroll
        for (int e = 0; e < 8; ++e) acc[e] = 0.f;
#pragma unroll
        for (int jj = 0; jj < 4; ++jj) {
            const int i = 256 * jj + 4 * lane;
            const float4 xv = *(const float4*)(x + (size_t)n * D_IN + i);
            ushort4 u;
            u.x = f2bf(xv.x); u.y = f2bf(xv.y);
            u.z = f2bf(xv.z); u.w = f2bf(xv.w);
            *(ushort4*)(xb + (size_t)n * D_IN + i) = u;
            const float xs[4] = {xv.x, xv.y, xv.z, xv.w};
#pragma unroll
            for (int j = 0; j < 4; ++j) {
                const float* wr = gW + (size_t)(i + j) * N_EXP;
                const float4 w0 = *(const float4*)wr;
                const float4 w1 = *(const float4*)(wr + 4);
                acc[0] += xs[j] * w0.x; acc[1] += xs[j] * w0.y;
                acc[2] += xs[j] * w0.z; acc[3] += xs[j] * w0.w;
                acc[4] += xs[j] * w1.x; acc[5] += xs[j] * w1.y;
                acc[6] += xs[j] * w1.z; acc[7] += xs[j] * w1.w;
            }
        }
#pragma unroll
        for (int off = 32; off > 0; off >>= 1) {
#pragma unroll
            for (int e = 0; e < 8; ++e) acc[e] += __shfl_down(acc[e], off);
        }
        if (lane == 0) {
            float lg[8], mx = -1e30f;
#pragma unroll
            for (int e = 0; e < 8; ++e) {
                lg[e] = acc[e] + gbias[e];
                mx = fmaxf(mx, lg[e]);
            }
            float s = 0.f;
#pragma unroll
            for (int e = 0; e < 8; ++e) { lg[e] = expf(lg[e] - mx); s += lg[e]; }
            const float inv = 1.f / s;
#pragma unroll
            for (int e = 0; e < 8; ++e)
                g_t[(size_t)e * N_TOK + n] = lg[e] * inv;
        }
    }
}

// ---------------------------------------------------------------------------
// GEMM: 128x128 tile, BK=32, double-buffered LDS: tile kt+1's
// global_load_lds issued BEFORE compute on tile kt, one barrier per
// iteration (drains next-tile loads after a full compute phase in flight).
// XCD swizzle: each XCD owns an 8x8 super-tile of blocks (A rows shared
// x8 within the XCD's L2 instead of streamed from L3 per expert).
// Telescoping gate rescale at expert boundaries (kt%32==0); bias via
// epilogue rank-8 update; plain stores.
// ---------------------------------------------------------------------------
__global__ __launch_bounds__(256, 2) void moe_gemm5_kernel(
    const unsigned short* __restrict__ xb,   // [N_TOK][D_IN] bf16
    const unsigned short* __restrict__ Wt,   // [D_OUT][KTOT] bf16
    const float* __restrict__ bias,          // [N_EXP][D_OUT]
    const float* __restrict__ g_t,           // [N_EXP][N_TOK]
    float* __restrict__ out) {               // [N_TOK][D_OUT]
    __shared__ __align__(16) unsigned short Abuf[2][128 * 32];  // 16 KB
    __shared__ __align__(16) unsigned short Bbuf[2][128 * 32];  // 16 KB
    __shared__ __align__(16) float g_s[N_EXP][128];
    __shared__ __align__(16) float r_s[N_EXP][128];  // [e>=1]=d[e-1]/d[e]; [0]=d[7]
    __shared__ __align__(16) float b_s[N_EXP][128];

    const int t    = threadIdx.x;
    const int lane = t & 63;
    const int ln15 = lane & 15;
    const int quad = lane >> 4;
    const int wave = t >> 6;
    const int wm0  = (wave >> 1) * 64;
    const int wn0  = (wave & 1) * 64;

    // XCD swizzle: flat -> (x', y') s.t. assuming xcd = flat % 8, each XCD
    // hosts x' = 0..7 crossed with 8 consecutive y' (one 8x8 super-tile).
    const int flat = blockIdx.x + 8 * blockIdx.y;       // grid (8, 64)
    const int xs_  = (flat >> 3) & 7;
    const int ys_  = ((flat & 7) << 3) | (flat >> 6);
    const int bn0  = xs_ * 128;
    const int bm0  = ys_ * 128;

    for (int j = t; j < N_EXP * 128; j += 256) {
        const int e = j >> 7, r = j & 127;
        g_s[e][r] = g_t[(size_t)e * N_TOK + bm0 + r];
        b_s[e][r] = bias[(size_t)e * D_OUT + bn0 + r];
    }
    __syncthreads();
    if (t < 128) {
        float d[N_EXP];
#pragma unroll
        for (int e = 0; e < N_EXP; ++e) d[e] = fmaxf(g_s[e][t], 1e-30f);
#pragma unroll
        for (int e = 1; e < N_EXP; ++e) r_s[e][t] = d[e - 1] / d[e];
        r_s[0][t] = d[N_EXP - 1];
    }

    f32x4 acc[4][4];
#pragma unroll
    for (int mi = 0; mi < 4; ++mi)
#pragma unroll
        for (int ni = 0; ni < 4; ++ni)
            acc[mi][ni] = (f32x4){0.f, 0.f, 0.f, 0.f};

    // wave-uniform staging bases (HW adds lane*16B)
    unsigned short* aL0[2] = {&Abuf[0][wave * 512], &Abuf[1][wave * 512]};
    unsigned short* aL1[2] = {&Abuf[0][2048 + wave * 512],
                              &Abuf[1][2048 + wave * 512]};
    unsigned short* bL0[2] = {&Bbuf[0][wave * 512], &Bbuf[1][wave * 512]};
    unsigned short* bL1[2] = {&Bbuf[0][2048 + wave * 512],
                              &Bbuf[1][2048 + wave * 512]};

    const unsigned short* ga =
        xb + (size_t)(bm0 + (t >> 2)) * D_IN + (t & 3) * 8;
    const unsigned short* gbB =
        Wt + (size_t)(bn0 + (t >> 2)) * KTOT + (t & 3) * 8;

    // prologue: stage tile 0 into buf 0
    load_lds16(ga, aL0[0]);
    load_lds16(ga + 64 * D_IN, aL1[0]);
    load_lds16(gbB, bL0[0]);
    load_lds16(gbB + 64 * KTOT, bL1[0]);
    __syncthreads();  // drains tile-0 loads; r_s also ready

    // flattened K loop: kt = e*32 + kk. B offset = kt*32; A offset = (kt&31)*32.
    for (int kt = 0; kt < 256; ++kt) {
        const int cb  = kt & 1;
        const int nb  = cb ^ 1;
        const int kt1 = (kt + 1) & 255;   // wraps harmlessly at kt=255

        // issue NEXT tile's staging loads (in flight during compute)
        load_lds16(ga + (kt1 & 31) * 32,              aL0[nb]);
        load_lds16(ga + 64 * D_IN + (kt1 & 31) * 32,  aL1[nb]);
        load_lds16(gbB + kt1 * 32,                    bL0[nb]);
        load_lds16(gbB + 64 * KTOT + kt1 * 32,        bL1[nb]);

        // telescoping rescale at expert boundary
        if (kt && !(kt & 31)) {
            const int e = kt >> 5;
#pragma unroll
            for (int mi = 0; mi < 4; ++mi) {
                const f32x4 rv = *(const f32x4*)&r_s[e][wm0 + mi * 16 + quad * 4];
#pragma unroll
                for (int ni = 0; ni < 4; ++ni)
#pragma unroll
                    for (int r = 0; r < 4; ++r) acc[mi][ni][r] *= rv[r];
            }
        }

        // compute on current buffer
        short8 af[4], bv[4];
#pragma unroll
        for (int mi = 0; mi < 4; ++mi)
            af[mi] = *(const short8*)
                &Abuf[cb][(wm0 + mi * 16 + ln15) * 32 + quad * 8];
#pragma unroll
        for (int ni = 0; ni < 4; ++ni)
            bv[ni] = *(const short8*)
                &Bbuf[cb][(wn0 + ni * 16 + ln15) * 32 + quad * 8];
#pragma unroll
        for (int mi = 0; mi < 4; ++mi)
#pragma unroll
            for (int ni = 0; ni < 4; ++ni)
                acc[mi][ni] = __builtin_amdgcn_mfma_f32_16x16x32_bf16(
                    af[mi], bv[ni], acc[mi][ni], 0, 0, 0);

        // one barrier: drains next-tile loads (had full compute in flight)
        // and this tile's ds_reads before buffers are reused.
        __syncthreads();
    }

    // final telescope scale by d[7], then add sum_e g_e * b[e][col]
#pragma unroll
    for (int mi = 0; mi < 4; ++mi) {
        const f32x4 fin = *(const f32x4*)&r_s[0][wm0 + mi * 16 + quad * 4];
#pragma unroll
        for (int ni = 0; ni < 4; ++ni)
#pragma unroll
            for (int r = 0; r < 4; ++r) acc[mi][ni][r] *= fin[r];
    }
#pragma unroll
    for (int e = 0; e < N_EXP; ++e) {
        f32x4 gv[4];
        float bv[4];
#pragma unroll
        for (int mi = 0; mi < 4; ++mi)
            gv[mi] = *(const f32x4*)&g_s[e][wm0 + mi * 16 + quad * 4];
#pragma unroll
        for (int ni = 0; ni < 4; ++ni) bv[ni] = b_s[e][wn0 + ni * 16 + ln15];
#pragma unroll
        for (int mi = 0; mi < 4; ++mi)
#pragma unroll
            for (int ni = 0; ni < 4; ++ni)
#pragma unroll
                for (int r = 0; r < 4; ++r)
                    acc[mi][ni][r] += gv[mi][r] * bv[ni];
    }

#pragma unroll
    for (int mi = 0; mi < 4; ++mi) {
#pragma unroll
        for (int ni = 0; ni < 4; ++ni) {
            const int col  = bn0 + wn0 + ni * 16 + ln15;
            const int row0 = bm0 + wm0 + mi * 16 + quad * 4;
#pragma unroll
            for (int r = 0; r < 4; ++r)
                out[(size_t)(row0 + r) * D_OUT + col] = acc[mi][ni][r];
        }
    }
}

// ---------------------------------------------------------------------------
extern "C" void kernel_launch(void* const* d_in, const int* in_sizes, int n_in,
                              void* d_out, int out_size, void* d_ws, size_t ws_size,
                              hipStream_t stream) {
    const float* x  = (const float*)d_in[0];
    const float* W  = (const float*)d_in[1];
    const float* b  = (const float*)d_in[2];
    const float* gW = (const float*)d_in[3];
    const float* gb = (const float*)d_in[4];
    float* out = (float*)d_out;

    unsigned short* xb  = (unsigned short*)d_ws;                 // 16 MB
    unsigned short* Wt  = xb + (size_t)N_TOK * D_IN;             // 16 MB
    float*          g_t = (float*)(Wt + (size_t)D_OUT * KTOT);   // 256 KB

    prep_kernel<<<4096, 256, 0, stream>>>(x, gW, gb, W, xb, Wt, g_t);
    moe_gemm5_kernel<<<dim3(D_OUT / 128, N_TOK / 128), 256, 0, stream>>>(
        xb, Wt, b, g_t, out);
}

// Round 7
// 281.770 us; speedup vs baseline: 1.0039x; 1.0039x over previous
//
#include <hip/hip_runtime.h>
#include <hip/hip_bf16.h>
#include <cstdint>
#include <cstddef>

#define N_TOK 8192
#define D_IN  1024
#define D_OUT 1024
#define N_EXP 8
#define KTOT  (N_EXP * D_IN)

typedef __attribute__((ext_vector_type(8))) short short8;
typedef __attribute__((ext_vector_type(8))) unsigned short ushort8;
typedef __attribute__((ext_vector_type(4))) float f32x4;

__device__ __forceinline__ unsigned short f2bf(float f) {
    union { float f; unsigned int u; } v; v.f = f;
    return (unsigned short)((v.u + 0x7FFFu + ((v.u >> 16) & 1u)) >> 16);
}

__device__ __forceinline__ void load_lds16(const void* g, void* l) {
    __builtin_amdgcn_global_load_lds(
        (const __attribute__((address_space(1))) void*)g,
        (__attribute__((address_space(3))) void*)l,
        16, 0, 0);
}

// ---------------------------------------------------------------------------
// Fused prep, 4096 blocks (unchanged):
//   [0,2048)    : W[e][i][o] fp32 -> Wt[o][e*1024+i] bf16 (64x64 transpose)
//   [2048,4096) : gate softmax + x->bf16, one wave per token (4 tok/block)
// ---------------------------------------------------------------------------
__global__ __launch_bounds__(256) void prep_kernel(
    const float* __restrict__ x, const float* __restrict__ gW,
    const float* __restrict__ gbias, const float* __restrict__ W,
    unsigned short* __restrict__ xb, unsigned short* __restrict__ Wt,
    float* __restrict__ g_t) {
    const int b = blockIdx.x;
    const int t = threadIdx.x;

    if (b < 2048) {
        __shared__ float tile[64][65];
        const int e  = b >> 8;
        const int i0 = ((b >> 4) & 15) * 64;
        const int o0 = (b & 15) * 64;

        const int rr = t >> 4;
        const int rc = (t & 15) * 4;
#pragma unroll
        for (int j = 0; j < 4; ++j) {
            const float4 v = *(const float4*)(
                W + ((size_t)e * D_IN + (i0 + rr + 16 * j)) * D_OUT + o0 + rc);
            tile[rr + 16 * j][rc + 0] = v.x;
            tile[rr + 16 * j][rc + 1] = v.y;
            tile[rr + 16 * j][rc + 2] = v.z;
            tile[rr + 16 * j][rc + 3] = v.w;
        }
        __syncthreads();
        const int ow = t >> 2;
        const int c  = (t & 3) * 16;
        ushort8 v0, v1;
#pragma unroll
        for (int j = 0; j < 8; ++j) v0[j] = f2bf(tile[c + j][ow]);
#pragma unroll
        for (int j = 0; j < 8; ++j) v1[j] = f2bf(tile[c + 8 + j][ow]);
        unsigned short* dst = Wt + (size_t)(o0 + ow) * KTOT + e * D_IN + i0 + c;
        *(ushort8*)dst = v0;
        *(ushort8*)(dst + 8) = v1;
    } else {
        const int lane = t & 63;
        const int n    = (b - 2048) * 4 + (t >> 6);

        float acc[8];
#pragma unroll
        for (int e = 0; e < 8; ++e) acc[e] = 0.f;
#pragma unroll
        for (int jj = 0; jj < 4; ++jj) {
            const int i = 256 * jj + 4 * lane;
            const float4 xv = *(const float4*)(x + (size_t)n * D_IN + i);
            ushort4 u;
            u.x = f2bf(xv.x); u.y = f2bf(xv.y);
            u.z = f2bf(xv.z); u.w = f2bf(xv.w);
            *(ushort4*)(xb + (size_t)n * D_IN + i) = u;
            const float xs[4] = {xv.x, xv.y, xv.z, xv.w};
#pragma unroll
            for (int j = 0; j < 4; ++j) {
                const float* wr = gW + (size_t)(i + j) * N_EXP;
                const float4 w0 = *(const float4*)wr;
                const float4 w1 = *(const float4*)(wr + 4);
                acc[0] += xs[j] * w0.x; acc[1] += xs[j] * w0.y;
                acc[2] += xs[j] * w0.z; acc[3] += xs[j] * w0.w;
                acc[4] += xs[j] * w1.x; acc[5] += xs[j] * w1.y;
                acc[6] += xs[j] * w1.z; acc[7] += xs[j] * w1.w;
            }
        }
#pragma unroll
        for (int off = 32; off > 0; off >>= 1) {
#pragma unroll
            for (int e = 0; e < 8; ++e) acc[e] += __shfl_down(acc[e], off);
        }
        if (lane == 0) {
            float lg[8], mx = -1e30f;
#pragma unroll
            for (int e = 0; e < 8; ++e) {
                lg[e] = acc[e] + gbias[e];
                mx = fmaxf(mx, lg[e]);
            }
            float s = 0.f;
#pragma unroll
            for (int e = 0; e < 8; ++e) { lg[e] = expf(lg[e] - mx); s += lg[e]; }
            const float inv = 1.f / s;
#pragma unroll
            for (int e = 0; e < 8; ++e)
                g_t[(size_t)e * N_TOK + n] = lg[e] * inv;
        }
    }
}

// ---------------------------------------------------------------------------
// GEMM: R6 structure (128x128 tile, BK=32, dbuf prefetch, XCD super-tile
// swizzle, telescoping gate rescale) + LDS BANK-CONFLICT XOR SWIZZLE:
// k-chunk slot c' = c XOR ((row>>1)&3). Staged via permuted global source
// addresses (global_load_lds lane->slot map is fixed); fragment reads use
// quad XOR ((ln15>>1)&3). Turns the 8-way read conflict into free 2-way.
// ---------------------------------------------------------------------------
__global__ __launch_bounds__(256, 2) void moe_gemm6_kernel(
    const unsigned short* __restrict__ xb,   // [N_TOK][D_IN] bf16
    const unsigned short* __restrict__ Wt,   // [D_OUT][KTOT] bf16
    const float* __restrict__ bias,          // [N_EXP][D_OUT]
    const float* __restrict__ g_t,           // [N_EXP][N_TOK]
    float* __restrict__ out) {               // [N_TOK][D_OUT]
    __shared__ __align__(16) unsigned short Abuf[2][128 * 32];  // 16 KB
    __shared__ __align__(16) unsigned short Bbuf[2][128 * 32];  // 16 KB
    __shared__ __align__(16) float g_s[N_EXP][128];
    __shared__ __align__(16) float r_s[N_EXP][128];  // [e>=1]=d[e-1]/d[e]; [0]=d[7]
    __shared__ __align__(16) float b_s[N_EXP][128];

    const int t    = threadIdx.x;
    const int lane = t & 63;
    const int ln15 = lane & 15;
    const int quad = lane >> 4;
    const int wave = t >> 6;
    const int wm0  = (wave >> 1) * 64;
    const int wn0  = (wave & 1) * 64;

    // XCD swizzle: each XCD (flat % 8) owns an 8x8 super-tile of blocks.
    const int flat = blockIdx.x + 8 * blockIdx.y;       // grid (8, 64)
    const int xs_  = (flat >> 3) & 7;
    const int ys_  = ((flat & 7) << 3) | (flat >> 6);
    const int bn0  = xs_ * 128;
    const int bm0  = ys_ * 128;

    for (int j = t; j < N_EXP * 128; j += 256) {
        const int e = j >> 7, r = j & 127;
        g_s[e][r] = g_t[(size_t)e * N_TOK + bm0 + r];
        b_s[e][r] = bias[(size_t)e * D_OUT + bn0 + r];
    }
    __syncthreads();
    if (t < 128) {
        float d[N_EXP];
#pragma unroll
        for (int e = 0; e < N_EXP; ++e) d[e] = fmaxf(g_s[e][t], 1e-30f);
#pragma unroll
        for (int e = 1; e < N_EXP; ++e) r_s[e][t] = d[e - 1] / d[e];
        r_s[0][t] = d[N_EXP - 1];
    }

    f32x4 acc[4][4];
#pragma unroll
    for (int mi = 0; mi < 4; ++mi)
#pragma unroll
        for (int ni = 0; ni < 4; ++ni)
            acc[mi][ni] = (f32x4){0.f, 0.f, 0.f, 0.f};

    // wave-uniform staging bases (HW adds lane*16B)
    unsigned short* aL0[2] = {&Abuf[0][wave * 512], &Abuf[1][wave * 512]};
    unsigned short* aL1[2] = {&Abuf[0][2048 + wave * 512],
                              &Abuf[1][2048 + wave * 512]};
    unsigned short* bL0[2] = {&Bbuf[0][wave * 512], &Bbuf[1][wave * 512]};
    unsigned short* bL1[2] = {&Bbuf[0][2048 + wave * 512],
                              &Bbuf[1][2048 + wave * 512]};

    // Staging source: lane t fills LDS slot (row t>>2, chunk t&3); with the
    // XOR swizzle, slot chunk c' holds global chunk c = c' ^ ((row>>1)&3).
    const int csw = ((t & 3) ^ ((t >> 3) & 3)) * 8;
    const unsigned short* ga =
        xb + (size_t)(bm0 + (t >> 2)) * D_IN + csw;
    const unsigned short* gbB =
        Wt + (size_t)(bn0 + (t >> 2)) * KTOT + csw;

    // Fragment read swizzle: chunk slot = quad ^ ((ln15>>1)&3)
    const int ksw = (quad ^ ((ln15 >> 1) & 3)) * 8;

    // prologue: stage tile 0 into buf 0
    load_lds16(ga, aL0[0]);
    load_lds16(ga + 64 * D_IN, aL1[0]);
    load_lds16(gbB, bL0[0]);
    load_lds16(gbB + 64 * KTOT, bL1[0]);
    __syncthreads();  // drains tile-0 loads; r_s also ready

    for (int kt = 0; kt < 256; ++kt) {
        const int cb  = kt & 1;
        const int nb  = cb ^ 1;
        const int kt1 = (kt + 1) & 255;   // wraps harmlessly at kt=255

        // issue NEXT tile's staging loads (in flight during compute)
        load_lds16(ga + (kt1 & 31) * 32,              aL0[nb]);
        load_lds16(ga + 64 * D_IN + (kt1 & 31) * 32,  aL1[nb]);
        load_lds16(gbB + kt1 * 32,                    bL0[nb]);
        load_lds16(gbB + 64 * KTOT + kt1 * 32,        bL1[nb]);

        // telescoping rescale at expert boundary
        if (kt && !(kt & 31)) {
            const int e = kt >> 5;
#pragma unroll
            for (int mi = 0; mi < 4; ++mi) {
                const f32x4 rv = *(const f32x4*)&r_s[e][wm0 + mi * 16 + quad * 4];
#pragma unroll
                for (int ni = 0; ni < 4; ++ni)
#pragma unroll
                    for (int r = 0; r < 4; ++r) acc[mi][ni][r] *= rv[r];
            }
        }

        // compute on current buffer (swizzled fragment reads)
        short8 af[4], bv[4];
#pragma unroll
        for (int mi = 0; mi < 4; ++mi)
            af[mi] = *(const short8*)
                &Abuf[cb][(wm0 + mi * 16 + ln15) * 32 + ksw];
#pragma unroll
        for (int ni = 0; ni < 4; ++ni)
            bv[ni] = *(const short8*)
                &Bbuf[cb][(wn0 + ni * 16 + ln15) * 32 + ksw];
#pragma unroll
        for (int mi = 0; mi < 4; ++mi)
#pragma unroll
            for (int ni = 0; ni < 4; ++ni)
                acc[mi][ni] = __builtin_amdgcn_mfma_f32_16x16x32_bf16(
                    af[mi], bv[ni], acc[mi][ni], 0, 0, 0);

        __syncthreads();
    }

    // final telescope scale by d[7], then add sum_e g_e * b[e][col]
#pragma unroll
    for (int mi = 0; mi < 4; ++mi) {
        const f32x4 fin = *(const f32x4*)&r_s[0][wm0 + mi * 16 + quad * 4];
#pragma unroll
        for (int ni = 0; ni < 4; ++ni)
#pragma unroll
            for (int r = 0; r < 4; ++r) acc[mi][ni][r] *= fin[r];
    }
#pragma unroll
    for (int e = 0; e < N_EXP; ++e) {
        f32x4 gv[4];
        float bv[4];
#pragma unroll
        for (int mi = 0; mi < 4; ++mi)
            gv[mi] = *(const f32x4*)&g_s[e][wm0 + mi * 16 + quad * 4];
#pragma unroll
        for (int ni = 0; ni < 4; ++ni) bv[ni] = b_s[e][wn0 + ni * 16 + ln15];
#pragma unroll
        for (int mi = 0; mi < 4; ++mi)
#pragma unroll
            for (int ni = 0; ni < 4; ++ni)
#pragma unroll
                for (int r = 0; r < 4; ++r)
                    acc[mi][ni][r] += gv[mi][r] * bv[ni];
    }

#pragma unroll
    for (int mi = 0; mi < 4; ++mi) {
#pragma unroll
        for (int ni = 0; ni < 4; ++ni) {
            const int col  = bn0 + wn0 + ni * 16 + ln15;
            const int row0 = bm0 + wm0 + mi * 16 + quad * 4;
#pragma unroll
            for (int r = 0; r < 4; ++r)
                out[(size_t)(row0 + r) * D_OUT + col] = acc[mi][ni][r];
        }
    }
}

// ---------------------------------------------------------------------------
extern "C" void kernel_launch(void* const* d_in, const int* in_sizes, int n_in,
                              void* d_out, int out_size, void* d_ws, size_t ws_size,
                              hipStream_t stream) {
    const float* x  = (const float*)d_in[0];
    const float* W  = (const float*)d_in[1];
    const float* b  = (const float*)d_in[2];
    const float* gW = (const float*)d_in[3];
    const float* gb = (const float*)d_in[4];
    float* out = (float*)d_out;

    unsigned short* xb  = (unsigned short*)d_ws;                 // 16 MB
    unsigned short* Wt  = xb + (size_t)N_TOK * D_IN;             // 16 MB
    float*          g_t = (float*)(Wt + (size_t)D_OUT * KTOT);   // 256 KB

    prep_kernel<<<4096, 256, 0, stream>>>(x, gW, gb, W, xb, Wt, g_t);
    moe_gemm6_kernel<<<dim3(D_OUT / 128, N_TOK / 128), 256, 0, stream>>>(
        xb, Wt, b, g_t, out);
}